// Round 5
// baseline (125.799 us; speedup 1.0000x reference)
//
#include <hip/hip_runtime.h>
#include <cstddef>

constexpr float GAMMA = 0.99f;
constexpr float GLAM  = 0.99f * 0.95f;   // gamma * gae_lambda
constexpr float ENT_C = 0.01f;

constexpr int T = 65536;
constexpr int O = 8;
constexpr int S = 1048576;               // 2^20
constexpr int BLK = 256;

constexpr int OPPB   = 2047;             // opponent blocks (persistent; +1 agent = 2048 = 32 waves/CU)
constexpr int NPAIRS = O * S / 2;        // 4194304 row-pairs
constexpr int CHUNK  = T / BLK;          // 256 elements per thread in agent scan

typedef float f4 __attribute__((ext_vector_type(4)));

// ws layout (floats):
//   ws[0    .. 2046] : per-block coef-weighted ce partials
//   ws[2048 .. 4094] : per-block coef-weighted smooth-L1 partials
//   ws[4096]         : agent loss

__device__ __forceinline__ float row_ce(float l0, float l1, float l2,
                                        float l3, float l4, float l5, int a)
{
    float m  = fmaxf(fmaxf(fmaxf(l0, l1), fmaxf(l2, l3)), fmaxf(l4, l5));
    float se = __expf(l0 - m) + __expf(l1 - m) + __expf(l2 - m) +
               __expf(l3 - m) + __expf(l4 - m) + __expf(l5 - m);
    float tgt = (a == 0) ? l0 : (a == 1) ? l1 : (a == 2) ? l2 :
                (a == 3) ? l3 : (a == 4) ? l4 : l5;
    return (m + __logf(se)) - tgt;
}

__device__ __forceinline__ float sl1(float v0, float v1, float rw)
{
    float d  = v0 - (rw + GAMMA * v1);
    float ad = fabsf(d);
    return (ad < 1.f) ? 0.5f * d * d : ad - 0.5f;
}

__global__ __launch_bounds__(BLK)
void fused_kernel(const float* __restrict__ arew,
                  const float* __restrict__ alp,
                  const float* __restrict__ aval,
                  const float* __restrict__ aent,
                  const float* __restrict__ olp,
                  const int*   __restrict__ oact,
                  const float* __restrict__ oval,
                  const float* __restrict__ orew,
                  const float* __restrict__ ocoef,
                  float* __restrict__ ws)
{
    const int tid = threadIdx.x;
    __shared__ float s1[BLK], s2[BLK];

    if (blockIdx.x == 0) {
        // ----------------- agent loss: blocked reverse linear scan -----------------
        const int base = tid * CHUNK;

        float cR = 0.f, cG = 0.f;
        float nextv = aval[base + CHUNK];
        #pragma unroll 4
        for (int k4 = CHUNK - 4; k4 >= 0; k4 -= 4) {
            float4 r4 = *reinterpret_cast<const float4*>(&arew[base + k4]);
            float4 v4 = *reinterpret_cast<const float4*>(&aval[base + k4]);
            cR = GAMMA * cR + r4.w;  cG = GLAM * cG + (r4.w + GAMMA * nextv - v4.w);
            cR = GAMMA * cR + r4.z;  cG = GLAM * cG + (r4.z + GAMMA * v4.w  - v4.z);
            cR = GAMMA * cR + r4.y;  cG = GLAM * cG + (r4.y + GAMMA * v4.z  - v4.y);
            cR = GAMMA * cR + r4.x;  cG = GLAM * cG + (r4.x + GAMMA * v4.y  - v4.x);
            nextv = v4.x;
        }
        s1[tid] = cR; s2[tid] = cG;
        __syncthreads();

        if (tid == 0) {
            double aRd = 1.0, aGd = 1.0;
            for (int i = 0; i < CHUNK; ++i) { aRd *= 0.99; aGd *= 0.99 * 0.95; }
            const float aR = (float)aRd, aG = (float)aGd;
            float Rin = aval[T];
            float Gin = 0.f;
            for (int i = BLK - 1; i >= 0; --i) {
                float cr = s1[i], cg = s2[i];
                s1[i] = Rin; s2[i] = Gin;
                Rin = aR * Rin + cr;
                Gin = aG * Gin + cg;
            }
        }
        __syncthreads();
        float R = s1[tid], g = s2[tid];
        __syncthreads();

        float pl = 0.f, vl = 0.f;
        nextv = aval[base + CHUNK];
        #pragma unroll 4
        for (int k4 = CHUNK - 4; k4 >= 0; k4 -= 4) {
            float4 r4 = *reinterpret_cast<const float4*>(&arew[base + k4]);
            float4 v4 = *reinterpret_cast<const float4*>(&aval[base + k4]);
            float4 l4 = *reinterpret_cast<const float4*>(&alp [base + k4]);
            float4 e4 = *reinterpret_cast<const float4*>(&aent[base + k4]);

            R = GAMMA * R + r4.w; { float adv = R - v4.w; vl += 0.5f * adv * adv; }
            g = GLAM * g + (r4.w + GAMMA * nextv - v4.w); pl += -l4.w * g - ENT_C * e4.w;
            R = GAMMA * R + r4.z; { float adv = R - v4.z; vl += 0.5f * adv * adv; }
            g = GLAM * g + (r4.z + GAMMA * v4.w  - v4.z); pl += -l4.z * g - ENT_C * e4.z;
            R = GAMMA * R + r4.y; { float adv = R - v4.y; vl += 0.5f * adv * adv; }
            g = GLAM * g + (r4.y + GAMMA * v4.z  - v4.y); pl += -l4.y * g - ENT_C * e4.y;
            R = GAMMA * R + r4.x; { float adv = R - v4.x; vl += 0.5f * adv * adv; }
            g = GLAM * g + (r4.x + GAMMA * v4.y  - v4.x); pl += -l4.x * g - ENT_C * e4.x;
            nextv = v4.x;
        }
        s1[tid] = pl; s2[tid] = vl;
        __syncthreads();
        for (int stp = BLK / 2; stp > 0; stp >>= 1) {
            if (tid < stp) { s1[tid] += s1[tid + stp]; s2[tid] += s2[tid + stp]; }
            __syncthreads();
        }
        if (tid == 0) ws[4096] = s1[0] + 0.5f * s2[0];
        return;
    }

    // -------- opponent loss: persistent blocks, grid-stride over row-pairs --------
    const int bid    = blockIdx.x - 1;           // 0 .. OPPB-1
    const int gtid   = bid * BLK + tid;
    const int stride = OPPB * BLK;

    float ce_acc = 0.f, sl_acc = 0.f;

    for (int p = gtid; p < NPAIRS; p += stride) {
        const int rr   = 2 * p;                  // flat row index (fits int: < 2^23)
        const int o    = rr >> 20;               // / S
        const int srel = rr & (S - 1);
        const float coef = ocoef[o];             // 32 B table, L1-resident

        const f4* Lp = reinterpret_cast<const f4*>(olp) + (size_t)p * 3;
        f4 q0 = Lp[0], q1 = Lp[1], q2 = Lp[2];
        int2   ac  = *reinterpret_cast<const int2*>(oact + rr);
        float2 v01 = *reinterpret_cast<const float2*>(oval + rr);

        const bool last = (srel == S - 2);       // 2nd row of pair is final row of this o
        float v2  = last ? 0.f : oval[rr + 2];
        float rw0 = orew[rr - o];                // o*(S-1) + srel == rr - o
        float rw1 = last ? 0.f : orew[rr - o + 1];

        float ce = row_ce(q0[0], q0[1], q0[2], q0[3], q1[0], q1[1], ac.x)
                 + row_ce(q1[2], q1[3], q2[0], q2[1], q2[2], q2[3], ac.y);
        float sl = sl1(v01.x, v01.y, rw0);
        if (!last) sl += sl1(v01.y, v2, rw1);

        ce_acc += coef * ce;
        sl_acc += coef * sl;
    }

    s1[tid] = ce_acc; s2[tid] = sl_acc;
    __syncthreads();
    for (int stp = BLK / 2; stp > 0; stp >>= 1) {
        if (tid < stp) { s1[tid] += s1[tid + stp]; s2[tid] += s2[tid + stp]; }
        __syncthreads();
    }
    if (tid == 0) {
        ws[bid]        = s1[0];
        ws[2048 + bid] = s2[0];
    }
}

__global__ __launch_bounds__(BLK)
void finalize_kernel(const float* __restrict__ ws, float* __restrict__ out)
{
    const int tid = threadIdx.x;
    __shared__ float r1[BLK], r2[BLK];
    float c = 0.f, s = 0.f;
    for (int i = tid; i < OPPB; i += BLK) {
        c += ws[i];
        s += ws[2048 + i];
    }
    r1[tid] = c; r2[tid] = s;
    __syncthreads();
    for (int stp = BLK / 2; stp > 0; stp >>= 1) {
        if (tid < stp) { r1[tid] += r1[tid + stp]; r2[tid] += r2[tid + stp]; }
        __syncthreads();
    }
    if (tid == 0)
        out[0] = r1[0] / (float)S + r2[0] / (float)(S - 1) + ws[4096];
}

extern "C" void kernel_launch(void* const* d_in, const int* in_sizes, int n_in,
                              void* d_out, int out_size, void* d_ws, size_t ws_size,
                              hipStream_t stream)
{
    const float* arew  = (const float*)d_in[0];
    const float* alp   = (const float*)d_in[1];
    const float* aval  = (const float*)d_in[2];
    const float* aent  = (const float*)d_in[3];
    const float* olp   = (const float*)d_in[4];
    const int*   oact  = (const int*)  d_in[5];
    const float* oval  = (const float*)d_in[6];
    const float* orew  = (const float*)d_in[7];
    const float* ocoef = (const float*)d_in[8];
    float* ws = (float*)d_ws;

    fused_kernel<<<1 + OPPB, BLK, 0, stream>>>(arew, alp, aval, aent,
                                               olp, oact, oval, orew, ocoef, ws);
    finalize_kernel<<<1, BLK, 0, stream>>>(ws, (float*)d_out);
}